// Round 1
// 119.824 us; speedup vs baseline: 1.3405x; 1.3405x over previous
//
#include <hip/hip_runtime.h>
#include <cstddef>

namespace {
constexpr int Z    = 4;
constexpr int N    = 256;
constexpr int CIN  = 32;
constexpr int COUT = 32;
constexpr int HID  = 64;
constexpr int OC   = COUT * CIN;  // 1024
}

// ---------------------------------------------------------------------------
// Kernel A: M[z][b][h4][i][hl] = sum_j W2[h][i*32+j] * f[z][b][j],  h = h4*4+hl
//           (h4-interleaved layout so kernel B's per-(b,i) float4 loads are
//            two dense 512B transactions per wave)
//           bf[z][b][i] = sum_j b2[i*32+j] * f[z][b][j]
// grid: Z * 64 * 4 = 1024 blocks (z, b-quad, quarter), 256 threads.
// 4 blocks/CU of work (was 1 -> latency-bound). W2 stays L2-resident.
// Stores are lane-contiguous (o = q*512 + p*256 + t).
// ---------------------------------------------------------------------------
__global__ __launch_bounds__(256) void precompute_M(
    const float* __restrict__ features,
    const float* __restrict__ W2,
    const float* __restrict__ b2,
    float* __restrict__ Mws,
    float* __restrict__ bfws)
{
    __shared__ __align__(16) float f_lds[4 * CIN];
    const int blk = blockIdx.x;          // ((z*64 + b4)*4 + q)
    const int q   = blk & 3;
    const int b4  = (blk >> 2) & 63;
    const int z   = blk >> 8;
    const int b0  = b4 << 2;
    const int t   = threadIdx.x;

    if (t < 4 * CIN) f_lds[t] = features[(z * N + b0) * CIN + t];
    __syncthreads();

    const float4* f4 = reinterpret_cast<const float4*>(f_lds);  // [4][8]

#pragma unroll
    for (int p = 0; p < 2; ++p) {
        const int o  = q * 512 + p * 256 + t;  // 0..2047 inside b's 2048-float slab
        const int h4 = o >> 7;
        const int i  = (o >> 2) & 31;
        const int hl = o & 3;
        const int hh = h4 * 4 + hl;
        const float4* w2r = reinterpret_cast<const float4*>(W2 + hh * OC + i * CIN);
        float4 w[8];
#pragma unroll
        for (int k = 0; k < 8; ++k) w[k] = w2r[k];
#pragma unroll
        for (int bl = 0; bl < 4; ++bl) {
            float v = 0.f;
#pragma unroll
            for (int k = 0; k < 8; ++k) {
                const float4 f = f4[bl * 8 + k];
                v += w[k].x * f.x + w[k].y * f.y + w[k].z * f.z + w[k].w * f.w;
            }
            // lane-contiguous store: consecutive t -> consecutive floats
            Mws[(size_t)(z * N + b0 + bl) * 2048 + o] = v;
        }
    }

    // bf for this quarter's i-range: i in [8q, 8q+8)
    if (t < 32) {
        const int bl = t >> 3;
        const int i  = q * 8 + (t & 7);
        const float4* b2r = reinterpret_cast<const float4*>(b2 + i * CIN);
        float v = 0.f;
#pragma unroll
        for (int k = 0; k < 8; ++k) {
            const float4 bb = b2r[k];
            const float4 f  = f4[bl * 8 + k];
            v += bb.x * f.x + bb.y * f.y + bb.z * f.z + bb.w * f.w;
        }
        bfws[(z * N + b0 + bl) * COUT + i] = v;
    }
}

// ---------------------------------------------------------------------------
// Kernel B: (z, a-block)-major so out writes are contiguous per-a slabs.
// Block = a-block(8 a's) x (z, b-octant of 32 b's): 1024 blocks, 256 threads.
//   thread = (b_local = t>>5, i = t&31); M[b,i,0:64] held in 16 float4 regs.
//   Per b-tile (8 b's): compute H[a][b_local][h] into small LDS (17 KiB),
//   then out[z,a,b,i] = bf[b,i] + sum_h H[a,b,h] * M[b,i,h].
// blockIdx = ablk*32 + (z*8 + boct): blockIdx%8 == boct, so each XCD's L2
// keeps its 1 MiB M slice resident across the 32 a-blocks that reuse it.
// Out stores: per wave 256 B contiguous, full lines (no 32KB-stride scatter).
// ---------------------------------------------------------------------------
__global__ __launch_bounds__(256, 4) void pair_contract(
    const float* __restrict__ geometry,
    const float* __restrict__ W1,
    const float* __restrict__ b1,
    const float* __restrict__ Mws,
    const float* __restrict__ bfws,
    float* __restrict__ out)
{
    __shared__ __align__(16) float Hs[64 * 68];   // [pair p = aa*8+bl][64h pad 68]
    __shared__ __align__(16) float w1l[4 * HID];  // W1 rows x=0,1,2 then b1

    const int blk   = blockIdx.x;     // ablk*32 + z*8 + boct
    const int combo = blk & 31;
    const int ablk  = blk >> 5;       // 0..31
    const int z     = combo >> 3;
    const int boct  = combo & 7;
    const int t     = threadIdx.x;

    if (t < 192)      w1l[t] = W1[t];
    else              w1l[t] = b1[t - 192];

    const int i  = t & 31;
    const int bl = t >> 5;            // 0..7
    const int a0 = ablk * 8;

    // H-phase mapping: pair p = (aa,bb), 4 threads per pair each do 16 h.
    const int p    = t >> 2;
    const int aa_h = p >> 3;
    const int bb_h = p & 7;
    const int h0   = (t & 3) * 16;

    // g_a is fixed for this thread across all tiles
    const float gax = geometry[(z * N + a0 + aa_h) * 3 + 0];
    const float gay = geometry[(z * N + a0 + aa_h) * 3 + 1];
    const float gaz = geometry[(z * N + a0 + aa_h) * 3 + 2];
    __syncthreads();

    for (int bt = 0; bt < 4; ++bt) {
        const int bbase = boct * 32 + bt * 8;
        const int b     = bbase + bl;

        // Issue M loads early (hidden under H phase). Two dense 512B
        // transactions per wave per qq.
        const float4* mp = reinterpret_cast<const float4*>(
            Mws + (size_t)(z * N + b) * 2048);
        float4 M[16];
#pragma unroll
        for (int qq = 0; qq < 16; ++qq) M[qq] = mp[qq * 32 + i];
        const float bfv = bfws[(z * N + b) * COUT + i];

        // H phase: H[p][h] = relu((g_b - g_a) . W1[:,h] + b1[h])
        {
            const int gb = bbase + bb_h;
            const float dx = geometry[(z * N + gb) * 3 + 0] - gax;
            const float dy = geometry[(z * N + gb) * 3 + 1] - gay;
            const float dz = geometry[(z * N + gb) * 3 + 2] - gaz;
#pragma unroll
            for (int hq = 0; hq < 16; hq += 4) {
                const int h = h0 + hq;
                const float4 w0  = *reinterpret_cast<const float4*>(&w1l[h]);
                const float4 w1v = *reinterpret_cast<const float4*>(&w1l[HID + h]);
                const float4 w2v = *reinterpret_cast<const float4*>(&w1l[2 * HID + h]);
                const float4 bb4 = *reinterpret_cast<const float4*>(&w1l[3 * HID + h]);
                float4 hv;
                hv.x = fmaxf(dx * w0.x + dy * w1v.x + dz * w2v.x + bb4.x, 0.f);
                hv.y = fmaxf(dx * w0.y + dy * w1v.y + dz * w2v.y + bb4.y, 0.f);
                hv.z = fmaxf(dx * w0.z + dy * w1v.z + dz * w2v.z + bb4.z, 0.f);
                hv.w = fmaxf(dx * w0.w + dy * w1v.w + dz * w2v.w + bb4.w, 0.f);
                *reinterpret_cast<float4*>(&Hs[p * 68 + h]) = hv;
            }
        }
        __syncthreads();

        // Contraction: 8 a's, dot64 each. Hs reads: 2 broadcast addrs/wave,
        // rows 68 floats apart -> bank-offset 4, conflict-free.
#pragma unroll
        for (int aa = 0; aa < 8; ++aa) {
            const float* hrow = &Hs[(aa * 8 + bl) * 68];
            float acc = bfv;
#pragma unroll
            for (int qq = 0; qq < 16; ++qq) {
                const float4 h4v = *reinterpret_cast<const float4*>(&hrow[qq * 4]);
                acc += h4v.x * M[qq].x + h4v.y * M[qq].y +
                       h4v.z * M[qq].z + h4v.w * M[qq].w;
            }
            // per wave: 2 x 128 B adjacent = 256 B contiguous full-line store
            out[((size_t)(z * N + a0 + aa) * N + b) * COUT + i] = acc;
        }
        __syncthreads();
    }
}

extern "C" void kernel_launch(void* const* d_in, const int* in_sizes, int n_in,
                              void* d_out, int out_size, void* d_ws, size_t ws_size,
                              hipStream_t stream) {
    const float* features = (const float*)d_in[0];
    const float* geometry = (const float*)d_in[1];
    const float* W1 = (const float*)d_in[2];
    const float* b1 = (const float*)d_in[3];
    const float* W2 = (const float*)d_in[4];
    const float* b2 = (const float*)d_in[5];
    float* out = (float*)d_out;

    float* Mws  = (float*)d_ws;                          // Z*N*2048 = 2,097,152 floats
    float* bfws = Mws + (size_t)Z * N * 2048;            // + Z*N*COUT = 32,768 floats

    precompute_M<<<Z * 64 * 4, 256, 0, stream>>>(features, W2, b2, Mws, bfws);
    pair_contract<<<Z * 64 * 4, 256, 0, stream>>>(geometry, W1, b1, Mws, bfws, out);
}

// Round 2
// 114.651 us; speedup vs baseline: 1.4010x; 1.0451x over previous
//
#include <hip/hip_runtime.h>
#include <cstddef>

namespace {
constexpr int Z    = 4;
constexpr int N    = 256;
constexpr int CIN  = 32;
constexpr int COUT = 32;
constexpr int HID  = 64;
constexpr int OC   = COUT * CIN;  // 1024
}

// ---------------------------------------------------------------------------
// Kernel A: M[z][b][h4][i][hl] = sum_j W2[h][i*32+j] * f[z][b][j],  h = h4*4+hl
//           (h4-interleaved layout so kernel B's per-(b,i) float4 loads are
//            two dense 512B transactions per wave)
//           bf[z][b][i] = sum_j b2[i*32+j] * f[z][b][j]
// grid: Z * 64 * 4 = 1024 blocks (z, b-quad, quarter), 256 threads.
// ---------------------------------------------------------------------------
__global__ __launch_bounds__(256) void precompute_M(
    const float* __restrict__ features,
    const float* __restrict__ W2,
    const float* __restrict__ b2,
    float* __restrict__ Mws,
    float* __restrict__ bfws)
{
    __shared__ __align__(16) float f_lds[4 * CIN];
    const int blk = blockIdx.x;          // ((z*64 + b4)*4 + q)
    const int q   = blk & 3;
    const int b4  = (blk >> 2) & 63;
    const int z   = blk >> 8;
    const int b0  = b4 << 2;
    const int t   = threadIdx.x;

    if (t < 4 * CIN) f_lds[t] = features[(z * N + b0) * CIN + t];
    __syncthreads();

    const float4* f4 = reinterpret_cast<const float4*>(f_lds);  // [4][8]

#pragma unroll
    for (int p = 0; p < 2; ++p) {
        const int o  = q * 512 + p * 256 + t;  // 0..2047 inside b's 2048-float slab
        const int h4 = o >> 7;
        const int i  = (o >> 2) & 31;
        const int hl = o & 3;
        const int hh = h4 * 4 + hl;
        const float4* w2r = reinterpret_cast<const float4*>(W2 + hh * OC + i * CIN);
        float4 w[8];
#pragma unroll
        for (int k = 0; k < 8; ++k) w[k] = w2r[k];
#pragma unroll
        for (int bl = 0; bl < 4; ++bl) {
            float v = 0.f;
#pragma unroll
            for (int k = 0; k < 8; ++k) {
                const float4 f = f4[bl * 8 + k];
                v += w[k].x * f.x + w[k].y * f.y + w[k].z * f.z + w[k].w * f.w;
            }
            Mws[(size_t)(z * N + b0 + bl) * 2048 + o] = v;
        }
    }

    if (t < 32) {
        const int bl = t >> 3;
        const int i  = q * 8 + (t & 7);
        const float4* b2r = reinterpret_cast<const float4*>(b2 + i * CIN);
        float v = 0.f;
#pragma unroll
        for (int k = 0; k < 8; ++k) {
            const float4 bb = b2r[k];
            const float4 f  = f4[bl * 8 + k];
            v += bb.x * f.x + bb.y * f.y + bb.z * f.z + bb.w * f.w;
        }
        bfws[(z * N + b0 + bl) * COUT + i] = v;
    }
}

// ---------------------------------------------------------------------------
// Kernel B: block = 32 a's x 8 b's (aspect flipped vs prev round).
//   M per block: 8 b x 8 KiB = 64 KiB (was 256 KiB) -> worst-case M traffic
//   67 MB instead of 268 MB; loaded ONCE into regs, reused over 4 a-subtiles.
//   thread = (bl = t>>5 in 0..7, i = t&31); M[b0+bl, i, 0:64] in 16 float4.
//   Per a-subtile (8 a's): H[aa][bl][h] tile in LDS (17 KiB), then
//   out[z,a,b,i] = bf + sum_h H*M, scalar nt stores (256 B/wave contiguous).
// Out stores are NON-TEMPORAL so the 33.5 MB write stream doesn't evict the
// per-XCD M slice out of L2 (the round-1 failure mode: write-allocate
// thrashing forced every block's M fetch to HBM => 268 MB = 43 us).
// blk = grp*64 + ablk*8 + c, combo = grp*8 + c = z*32 + bblk: blocks sharing
// an M b-tile (same z,bblk) share blk%8 -> same XCD -> L2 hits.
// ---------------------------------------------------------------------------
__global__ __launch_bounds__(256, 4) void pair_contract(
    const float* __restrict__ geometry,
    const float* __restrict__ W1,
    const float* __restrict__ b1,
    const float* __restrict__ Mws,
    const float* __restrict__ bfws,
    float* __restrict__ out)
{
    __shared__ __align__(16) float Hs[64 * 68];   // [pair p = aa*8+bl][64h pad 68]
    __shared__ __align__(16) float w1l[4 * HID];  // W1 rows x=0,1,2 then b1
    __shared__ float gal[32 * 3];                 // a-geometry for this block
    __shared__ float gbl[8 * 3];                  // b-geometry for this block

    const int blk   = blockIdx.x;     // grp*64 + ablk*8 + c
    const int c     = blk & 7;
    const int ablk  = (blk >> 3) & 7; // 0..7  (N/32 a-blocks)
    const int grp   = blk >> 6;       // 0..15
    const int combo = grp * 8 + c;    // 0..127 = z*32 + bblk
    const int z     = combo >> 5;
    const int bblk  = combo & 31;     // 0..31 (N/8 b-blocks)
    const int b0    = bblk * 8;
    const int a0    = ablk * 32;
    const int t     = threadIdx.x;

    if (t < 192)               w1l[t]       = W1[t];
    else                       w1l[t]       = b1[t - 192];
    if (t >= 64 && t < 160)    gal[t - 64]  = geometry[(z * N + a0) * 3 + (t - 64)];
    if (t >= 160 && t < 184)   gbl[t - 160] = geometry[(z * N + b0) * 3 + (t - 160)];

    const int i  = t & 31;
    const int bl = t >> 5;            // 0..7

    // M[b0+bl, i, :] once per block: two dense 512B transactions per wave per qq.
    const float4* mp = reinterpret_cast<const float4*>(
        Mws + (size_t)(z * N + b0 + bl) * 2048);
    float4 M[16];
#pragma unroll
    for (int qq = 0; qq < 16; ++qq) M[qq] = mp[qq * 32 + i];
    const float bfv = bfws[(z * N + b0 + bl) * COUT + i];

    // H-phase mapping: pair p = (aa,bb), 4 threads per pair each do 16 h.
    const int p    = t >> 2;
    const int aa_h = p >> 3;
    const int bb_h = p & 7;
    const int h0   = (t & 3) * 16;

    __syncthreads();

    const float gbx = gbl[bb_h * 3 + 0];
    const float gby = gbl[bb_h * 3 + 1];
    const float gbz = gbl[bb_h * 3 + 2];

    for (int s = 0; s < 4; ++s) {
        // H phase: H[p][h] = relu((g_b - g_a) . W1[:,h] + b1[h]), a = a0+s*8+aa
        {
            const float gax = gal[(s * 8 + aa_h) * 3 + 0];
            const float gay = gal[(s * 8 + aa_h) * 3 + 1];
            const float gaz = gal[(s * 8 + aa_h) * 3 + 2];
            const float dx = gbx - gax, dy = gby - gay, dz = gbz - gaz;
#pragma unroll
            for (int hq = 0; hq < 16; hq += 4) {
                const int h = h0 + hq;
                const float4 w0  = *reinterpret_cast<const float4*>(&w1l[h]);
                const float4 w1v = *reinterpret_cast<const float4*>(&w1l[HID + h]);
                const float4 w2v = *reinterpret_cast<const float4*>(&w1l[2 * HID + h]);
                const float4 bb4 = *reinterpret_cast<const float4*>(&w1l[3 * HID + h]);
                float4 hv;
                hv.x = fmaxf(dx * w0.x + dy * w1v.x + dz * w2v.x + bb4.x, 0.f);
                hv.y = fmaxf(dx * w0.y + dy * w1v.y + dz * w2v.y + bb4.y, 0.f);
                hv.z = fmaxf(dx * w0.z + dy * w1v.z + dz * w2v.z + bb4.z, 0.f);
                hv.w = fmaxf(dx * w0.w + dy * w1v.w + dz * w2v.w + bb4.w, 0.f);
                *reinterpret_cast<float4*>(&Hs[p * 68 + h]) = hv;
            }
        }
        __syncthreads();

        // Contraction: 8 a's of this subtile, dot64 each against reg-held M.
#pragma unroll
        for (int aa = 0; aa < 8; ++aa) {
            const float* hrow = &Hs[(aa * 8 + bl) * 68];
            float acc = bfv;
#pragma unroll
            for (int qq = 0; qq < 16; ++qq) {
                const float4 h4v = *reinterpret_cast<const float4*>(&hrow[qq * 4]);
                acc += h4v.x * M[qq].x + h4v.y * M[qq].y +
                       h4v.z * M[qq].z + h4v.w * M[qq].w;
            }
            // per wave: 2 b x 128 B adjacent = 256 B contiguous; nt bypasses
            // L2 retention so M stays resident.
            __builtin_nontemporal_store(
                acc,
                &out[(((size_t)z * N + a0 + s * 8 + aa) * N + b0 + bl) * COUT + i]);
        }
        __syncthreads();
    }
}

extern "C" void kernel_launch(void* const* d_in, const int* in_sizes, int n_in,
                              void* d_out, int out_size, void* d_ws, size_t ws_size,
                              hipStream_t stream) {
    const float* features = (const float*)d_in[0];
    const float* geometry = (const float*)d_in[1];
    const float* W1 = (const float*)d_in[2];
    const float* b1 = (const float*)d_in[3];
    const float* W2 = (const float*)d_in[4];
    const float* b2 = (const float*)d_in[5];
    float* out = (float*)d_out;

    float* Mws  = (float*)d_ws;                          // Z*N*2048 = 2,097,152 floats
    float* bfws = Mws + (size_t)Z * N * 2048;            // + Z*N*COUT = 32,768 floats

    precompute_M<<<Z * 64 * 4, 256, 0, stream>>>(features, W2, b2, Mws, bfws);
    pair_contract<<<Z * 64 * 4, 256, 0, stream>>>(geometry, W1, b1, Mws, bfws, out);
}

// Round 3
// 90.292 us; speedup vs baseline: 1.7790x; 1.2698x over previous
//
#include <hip/hip_runtime.h>
#include <cstddef>

namespace {
constexpr int Z    = 4;
constexpr int N    = 256;
constexpr int CIN  = 32;
constexpr int COUT = 32;
constexpr int HID  = 64;
constexpr int OC   = COUT * CIN;  // 1024

typedef _Float16 f16x8 __attribute__((ext_vector_type(8)));
typedef float    f32x4 __attribute__((ext_vector_type(4)));
}

// ---------------------------------------------------------------------------
// Kernel A: M[z][b][i][h] = sum_j W2[h][i*32+j] * f[z][b][j], split into f16
// hi/lo planes laid out as [b][kc][i][j8] (kc = kb*4+quad, h = kb*32+quad*8+j)
// so kernel B's B-fragments are single dense 16B/lane loads.
// Grid 2048 x 64: block = (b-quad bg, slot-32nd p5), covering 16 (z,b) pairs
// per W2 read -> W2 HBM traffic 16.8 MB (was 67 MB).
// ---------------------------------------------------------------------------
__global__ __launch_bounds__(64) void precompute_M(
    const float* __restrict__ features,
    const float* __restrict__ W2,
    const float* __restrict__ b2,
    _Float16* __restrict__ Mh,
    _Float16* __restrict__ Ml,
    float* __restrict__ bfws)
{
    __shared__ __align__(16) float f_lds[16 * CIN];   // 16 (z,b) x 32 j
    const int blk = blockIdx.x;          // bg*32 + p5
    const int p5  = blk & 31;
    const int bg  = blk >> 5;            // 0..63 (b-quad)
    const int b0  = bg * 4;
    const int t   = threadIdx.x;         // 0..63

    // stage features for all 16 (z, b0..b0+3) pairs
#pragma unroll
    for (int r = 0; r < 8; ++r) {
        const int idx = r * 64 + t;      // 0..511: zb = idx>>5, j = idx&31
        const int zb = idx >> 5;
        f_lds[idx] = features[((zb >> 2) * N + b0 + (zb & 3)) * CIN + (idx & 31)];
    }
    __syncthreads();

    const int kc   = p5 >> 2;            // 0..7
    const int i    = (p5 & 3) * 8 + (t & 7);
    const int j    = t >> 3;             // 0..7  (consecutive lanes: i-contig)
    const int h    = (kc >> 2) * 32 + (kc & 3) * 8 + j;
    const int o    = kc * 256 + i * 8 + j;   // slot within b's 2048

    const float4* w2r = reinterpret_cast<const float4*>(W2 + h * OC + i * CIN);
    float4 w[8];
#pragma unroll
    for (int q = 0; q < 8; ++q) w[q] = w2r[q];

#pragma unroll
    for (int zb = 0; zb < 16; ++zb) {
        const float4* f4 = reinterpret_cast<const float4*>(&f_lds[zb * CIN]);
        float v = 0.f;
#pragma unroll
        for (int q = 0; q < 8; ++q) {
            const float4 f = f4[q];
            v += w[q].x * f.x + w[q].y * f.y + w[q].z * f.z + w[q].w * f.w;
        }
        const size_t base = (size_t)((zb >> 2) * N + b0 + (zb & 3)) * 2048 + o;
        const _Float16 hi = (_Float16)v;
        Mh[base] = hi;
        Ml[base] = (_Float16)(v - (float)hi);
    }

    // bf[z][b][i] = b2[i*32+..] . f   (p5 = 0,1 blocks, 4 zb per thread)
    if (p5 < 2) {
        const int ii = t & 31, half = t >> 5;
        const float4* b2r = reinterpret_cast<const float4*>(b2 + ii * CIN);
        float4 bb[8];
#pragma unroll
        for (int q = 0; q < 8; ++q) bb[q] = b2r[q];
#pragma unroll
        for (int s = 0; s < 4; ++s) {
            const int zb = p5 * 8 + half * 4 + s;
            const float4* f4 = reinterpret_cast<const float4*>(&f_lds[zb * CIN]);
            float v = 0.f;
#pragma unroll
            for (int q = 0; q < 8; ++q) {
                const float4 f = f4[q];
                v += bb[q].x * f.x + bb[q].y * f.y + bb[q].z * f.z + bb[q].w * f.w;
            }
            bfws[((zb >> 2) * N + b0 + (zb & 3)) * COUT + ii] = v;
        }
    }
}

// ---------------------------------------------------------------------------
// Kernel B: MFMA contraction, zero LDS. Block = 1 wave = 16 a x 4 b.
// Per b: lane computes its A-fragment H rows directly (m-row = a0+(l&15),
// k-chunk = (l>>4)*8), split fp32->f16 hi/lo; B-frags loaded 16B/lane from
// the pre-split M planes; 3-MFMA split product AhBh + AhBl + AlBh (err~1e-3).
// k-layout is self-consistent: A and B use the same (quad,j)->h placement,
// so any bijective HW k-map pairs them correctly.
// D layout (m89-verified): col i = l&15, row a = (l>>4)*4 + reg.
// blk = abk*256 + z*64 + bbk: the 16 a-blocks sharing one 32 KB M-tile are
// congruent mod 8 -> same XCD -> L2-resident M. nt dword stores in 64 B
// wave-chunks; block's out lines span many L2 sets (b in low addr bits).
// ---------------------------------------------------------------------------
__global__ __launch_bounds__(64) void pair_contract_mfma(
    const float* __restrict__ geometry,
    const float* __restrict__ W1,
    const float* __restrict__ b1,
    const _Float16* __restrict__ Mh,
    const _Float16* __restrict__ Ml,
    const float* __restrict__ bfws,
    float* __restrict__ out)
{
    const int blk  = blockIdx.x;         // abk*256 + z*64 + bbk
    const int abk  = blk >> 8;           // 0..15
    const int z    = (blk >> 6) & 3;
    const int bbk  = blk & 63;
    const int a0   = abk * 16;
    const int b0   = bbk * 4;
    const int l    = threadIdx.x;
    const int lo4  = l & 15;
    const int quad = l >> 4;             // 0..3

    // geometry of this lane's A-row
    const float gax = geometry[(z * N + a0 + lo4) * 3 + 0];
    const float gay = geometry[(z * N + a0 + lo4) * 3 + 1];
    const float gaz = geometry[(z * N + a0 + lo4) * 3 + 2];

    // W1 / b1 columns for this lane's h-slots: h = kb*32 + quad*8 + (half*4+jj)
    float4 w1f[3][2][2], b1f[2][2];
#pragma unroll
    for (int x = 0; x < 3; ++x)
#pragma unroll
        for (int kb = 0; kb < 2; ++kb)
#pragma unroll
            for (int hf = 0; hf < 2; ++hf)
                w1f[x][kb][hf] = *reinterpret_cast<const float4*>(
                    W1 + x * HID + kb * 32 + quad * 8 + hf * 4);
#pragma unroll
    for (int kb = 0; kb < 2; ++kb)
#pragma unroll
        for (int hf = 0; hf < 2; ++hf)
            b1f[kb][hf] = *reinterpret_cast<const float4*>(
                b1 + kb * 32 + quad * 8 + hf * 4);

    f32x4 acc[4][2];
#pragma unroll
    for (int bq = 0; bq < 4; ++bq)
#pragma unroll
        for (int nt = 0; nt < 2; ++nt) acc[bq][nt] = (f32x4)0.f;

#pragma unroll
    for (int bq = 0; bq < 4; ++bq) {
        const int b = b0 + bq;
        // B-fragment loads (issued early; dense 16 B/lane)
        const size_t mbase = (size_t)(z * N + b) * 2048;
        f16x8 Bh[2][2], Bl[2][2];
#pragma unroll
        for (int kb = 0; kb < 2; ++kb)
#pragma unroll
            for (int nt = 0; nt < 2; ++nt) {
                const size_t p = mbase +
                    (size_t)(((kb * 4 + quad) * 32) + nt * 16 + lo4) * 8;
                Bh[kb][nt] = *reinterpret_cast<const f16x8*>(Mh + p);
                Bl[kb][nt] = *reinterpret_cast<const f16x8*>(Ml + p);
            }

        // A-fragment: H = relu((g_b - g_a).W1 + b1), split hi/lo
        const float dx = geometry[(z * N + b) * 3 + 0] - gax;
        const float dy = geometry[(z * N + b) * 3 + 1] - gay;
        const float dz = geometry[(z * N + b) * 3 + 2] - gaz;
        f16x8 Ah[2], Al[2];
#pragma unroll
        for (int kb = 0; kb < 2; ++kb)
#pragma unroll
            for (int hf = 0; hf < 2; ++hf)
#pragma unroll
                for (int jj = 0; jj < 4; ++jj) {
                    float hv = b1f[kb][hf][jj];
                    hv = fmaf(dx, w1f[0][kb][hf][jj], hv);
                    hv = fmaf(dy, w1f[1][kb][hf][jj], hv);
                    hv = fmaf(dz, w1f[2][kb][hf][jj], hv);
                    hv = fmaxf(hv, 0.f);
                    const _Float16 hi = (_Float16)hv;
                    Ah[kb][hf * 4 + jj] = hi;
                    Al[kb][hf * 4 + jj] = (_Float16)(hv - (float)hi);
                }

        // 12 MFMAs: 2 n-tiles x 2 k-blocks x 3-term split
#pragma unroll
        for (int nt = 0; nt < 2; ++nt)
#pragma unroll
            for (int kb = 0; kb < 2; ++kb) {
                acc[bq][nt] = __builtin_amdgcn_mfma_f32_16x16x32_f16(
                    Ah[kb], Bh[kb][nt], acc[bq][nt], 0, 0, 0);
                acc[bq][nt] = __builtin_amdgcn_mfma_f32_16x16x32_f16(
                    Ah[kb], Bl[kb][nt], acc[bq][nt], 0, 0, 0);
                acc[bq][nt] = __builtin_amdgcn_mfma_f32_16x16x32_f16(
                    Al[kb], Bh[kb][nt], acc[bq][nt], 0, 0, 0);
            }
    }

    // Epilogue: acc + bf, nt stores. out[(z,a,b,i)], a = a0 + quad*4 + r.
#pragma unroll
    for (int bq = 0; bq < 4; ++bq) {
        const int b = b0 + bq;
#pragma unroll
        for (int nt = 0; nt < 2; ++nt) {
            const float bfv = bfws[(z * N + b) * COUT + nt * 16 + lo4];
#pragma unroll
            for (int r = 0; r < 4; ++r) {
                const int a = a0 + quad * 4 + r;
                __builtin_nontemporal_store(
                    acc[bq][nt][r] + bfv,
                    &out[((size_t)(z * N + a) * N + b) * COUT + nt * 16 + lo4]);
            }
        }
    }
}

extern "C" void kernel_launch(void* const* d_in, const int* in_sizes, int n_in,
                              void* d_out, int out_size, void* d_ws, size_t ws_size,
                              hipStream_t stream) {
    const float* features = (const float*)d_in[0];
    const float* geometry = (const float*)d_in[1];
    const float* W1 = (const float*)d_in[2];
    const float* b1 = (const float*)d_in[3];
    const float* W2 = (const float*)d_in[4];
    const float* b2 = (const float*)d_in[5];
    float* out = (float*)d_out;

    // workspace carve: Mh (4 MB) | Ml (4 MB) | bf (128 KB)
    _Float16* Mh  = (_Float16*)d_ws;
    _Float16* Ml  = Mh + (size_t)Z * N * 2048;
    float*    bfw = (float*)(Ml + (size_t)Z * N * 2048);

    precompute_M<<<64 * 32, 64, 0, stream>>>(features, W2, b2, Mh, Ml, bfw);
    pair_contract_mfma<<<16 * Z * 64, 64, 0, stream>>>(
        geometry, W1, b1, Mh, Ml, bfw, out);
}